// Round 7
// baseline (97.318 us; speedup 1.0000x reference)
//
#include <hip/hip_runtime.h>

#define HH 192
#define WW 192
#define BB 2
#define NC 6
#define FSZ 11
#define PAD 5
#define TW 16
#define TH 8
#define SW2 36             // staged cols for fused pair (TW + 4*PAD)
#define SH2 28             // staged rows (TH + 4*PAD)
#define LA1 37             // LDS row stride for A1/F2a
#define MW 26              // mid region cols (TW + 2*PAD)
#define MH 18              // mid region rows (TH + 2*PAD)
#define LA2 27             // LDS row stride for Q1
#define HW (HH*WW)
#define BT 512
#define NPAIR 234          // 18 rows x 13 col-pairs of the mid region

// bf16 pack/unpack (round-half-up)
__device__ __forceinline__ unsigned pkbf(float a, float b) {
    unsigned ua = (__float_as_uint(a) + 0x8000u) >> 16;
    unsigned ub = (__float_as_uint(b) + 0x8000u) & 0xffff0000u;
    return ua | ub;
}
__device__ __forceinline__ float lo16(unsigned u){ return __uint_as_float(u << 16); }
__device__ __forceinline__ float hi16(unsigned u){ return __uint_as_float(u & 0xffff0000u); }

__device__ __forceinline__ void build_sf(int tid, float s0, float s1, float isb,
                                         float swv, float awv, float* sfw, float* sfa)
{
    if (tid < FSZ*FSZ) {
        const int fi = tid / FSZ, fj = tid - (tid/FSZ)*FSZ;
        const float ri = (float)(fi-PAD) * s0 * isb;
        const float rj = (float)(fj-PAD) * s1 * isb;
        float sf = __expf(-0.5f*(ri*ri + rj*rj));
        if (fi == PAD && fj == PAD) sf = 0.f;
        sfw[tid] = sf * swv;
        sfa[tid] = sf * awv;
    }
}

// Two fused mean-field iterations.
//   stage 36x28 (q,f packed) -> pass1: 26x18 intermediate q in LDS
//   -> pass2: 16x8 tile -> packed q slab out.
// FIRST: stage from planar x (softmax on the fly) and also write f2 slab.
template<bool FIRST>
__global__ __launch_bounds__(BT, 4)
void crf_pair(const float* __restrict__ xpl, const uint4* __restrict__ Ain,
              const float* __restrict__ f2in, const float* __restrict__ feats,
              const float* __restrict__ spac, const float* __restrict__ swp,
              const float* __restrict__ awp, const float* __restrict__ isbp,
              const float* __restrict__ iabp,
              uint4* __restrict__ Aout, float* __restrict__ f2out)
{
    __shared__ uint4 A1[SH2][LA1];      // q01,q23,q45,f01 (bf16x2), prescaled f
    __shared__ float F2a[SH2][LA1];     // f2 (f32, prescaled)
    __shared__ uint4 Q1[MH][LA2];       // pass-1 output q (+f01 passthrough)
    __shared__ float sfw[FSZ*FSZ], sfa[FSZ*FSZ];
    __shared__ float pm[4][NC][132];    // pass-2 partials

    const int tid = threadIdx.x;
    const int b  = blockIdx.z;
    const int w0 = blockIdx.x * TW;
    const int h0 = blockIdx.y * TH;

    const float swv = swp[0], awv = awp[0], isb = isbp[0], iab = iabp[0];
    const float s0 = spac[b*2], s1 = spac[b*2+1];
    const float sfac = iab * 0.70710678f;   // af = exp(-sum((d*sfac)^2))

    build_sf(tid, s0, s1, isb, swv, awv, sfw, sfa);

    // ---- stage 28 x 37 (incl. pad col) ----
    for (int idx = tid; idx < SH2*LA1; idx += BT) {
        const int sr = idx / LA1, sc = idx - (idx/LA1)*LA1;
        const int gh = h0 - 2*PAD + sr, gw = w0 - 2*PAD + sc;
        uint4 av = make_uint4(0u,0u,0u,0u);
        float f2v = 0.f;
        if (gh >= 0 && gh < HH && gw >= 0 && gw < WW) {
            if (FIRST) {
                const int off = gh*WW + gw;
                const float* xb = xpl + (size_t)b*NC*HW + off;
                const float v0 = xb[0], v1 = xb[HW], v2 = xb[2*HW];
                const float v3 = xb[3*HW], v4 = xb[4*HW], v5 = xb[5*HW];
                float m = fmaxf(fmaxf(fmaxf(v0,v1),fmaxf(v2,v3)),fmaxf(v4,v5));
                float q0=__expf(v0-m), q1=__expf(v1-m), q2=__expf(v2-m);
                float q3=__expf(v3-m), q4=__expf(v4-m), q5=__expf(v5-m);
                const float rs = 1.0f/(q0+q1+q2+q3+q4+q5);
                const float* fb = feats + (size_t)b*3*HW + off;
                const float g0 = fb[0]*sfac, g1 = fb[HW]*sfac, g2 = fb[2*HW]*sfac;
                av = make_uint4(pkbf(q0*rs,q1*rs), pkbf(q2*rs,q3*rs),
                                pkbf(q4*rs,q5*rs), pkbf(g0,g1));
                f2v = g2;
            } else {
                const size_t p = (size_t)(b*HH + gh)*WW + gw;
                av  = Ain[p];
                f2v = f2in[p];
            }
        }
        A1[sr][sc]  = av;
        F2a[sr][sc] = f2v;
    }
    __syncthreads();

    // ---- pass 1: iter k over 26x18, px-pair x tap-half per thread ----
    {
        const int half = tid & 1;          // 0: taps j 0..5 ; 1: taps j 6..10
        const int pr   = tid >> 1;         // pair id
        if (pr < NPAIR) {
            const int r1 = pr / 13;
            const int c0 = (pr - r1*13) * 2;
            const int jb = half * 6;

            const unsigned cwA = A1[r1+PAD][c0+PAD].w;
            const unsigned cwB = A1[r1+PAD][c0+PAD+1].w;
            const float a0 = lo16(cwA), a1 = hi16(cwA), a2 = F2a[r1+PAD][c0+PAD];
            const float b0 = lo16(cwB), b1 = hi16(cwB), b2 = F2a[r1+PAD][c0+PAD+1];

            float mA[NC], mB[NC];
            #pragma unroll
            for (int c = 0; c < NC; ++c) { mA[c]=0.f; mB[c]=0.f; }

            #pragma unroll 1
            for (int i = 0; i < FSZ; ++i) {
                float srwR[6], sraR[6];
                #pragma unroll
                for (int d = 0; d < 6; ++d) {
                    const int jj = jb + d;
                    const bool v = (jj < FSZ);
                    srwR[d] = v ? sfw[i*FSZ + jj] : 0.f;
                    sraR[d] = v ? sfa[i*FSZ + jj] : 0.f;
                }
                const uint4* Ar = &A1[r1+i][c0+jb];
                const float* Fr = &F2a[r1+i][c0+jb];
                #pragma unroll
                for (int a = 0; a < 7; ++a) {
                    const uint4 av = Ar[a];
                    const float g2 = Fr[a];
                    const float q0 = lo16(av.x), q1 = hi16(av.x);
                    const float q2 = lo16(av.y), q3 = hi16(av.y);
                    const float q4 = lo16(av.z), q5 = hi16(av.z);
                    const float g0 = lo16(av.w), g1 = hi16(av.w);
                    if (a < 6) {          // pixel A, tap d=a
                        const float d0=a0-g0, d1=a1-g1, d2=a2-g2;
                        const float tt = fmaf(d2,d2, fmaf(d1,d1, d0*d0));
                        const float af = __expf(-tt);
                        const float tf = fmaf(af, sraR[a], srwR[a]);
                        mA[0]=fmaf(tf,q0,mA[0]); mA[1]=fmaf(tf,q1,mA[1]);
                        mA[2]=fmaf(tf,q2,mA[2]); mA[3]=fmaf(tf,q3,mA[3]);
                        mA[4]=fmaf(tf,q4,mA[4]); mA[5]=fmaf(tf,q5,mA[5]);
                    }
                    if (a >= 1) {         // pixel B, tap d=a-1
                        const float d0=b0-g0, d1=b1-g1, d2=b2-g2;
                        const float tt = fmaf(d2,d2, fmaf(d1,d1, d0*d0));
                        const float af = __expf(-tt);
                        const float tf = fmaf(af, sraR[a-1], srwR[a-1]);
                        mB[0]=fmaf(tf,q0,mB[0]); mB[1]=fmaf(tf,q1,mB[1]);
                        mB[2]=fmaf(tf,q2,mB[2]); mB[3]=fmaf(tf,q3,mB[3]);
                        mB[4]=fmaf(tf,q4,mB[4]); mB[5]=fmaf(tf,q5,mB[5]);
                    }
                }
            }

            // combine tap-halves (partner = lane^1, same pair)
            #pragma unroll
            for (int c = 0; c < NC; ++c) {
                mA[c] += __shfl_xor(mA[c], 1);
                mB[c] += __shfl_xor(mB[c], 1);
            }

            if (half == 0) {
                const int gh = h0 - PAD + r1;
                #pragma unroll
                for (int k = 0; k < 2; ++k) {
                    const int gw = w0 - PAD + c0 + k;
                    const float* msg = k ? mB : mA;
                    uint4 qv = make_uint4(0u,0u,0u,0u);
                    if (gh >= 0 && gh < HH && gw >= 0 && gw < WW) {
                        const float* up = xpl + (size_t)b*NC*HW + (size_t)gh*WW + gw;
                        float xn[NC];
                        #pragma unroll
                        for (int c = 0; c < NC; ++c) xn[c] = up[(size_t)c*HW] + msg[c];
                        float m = xn[0];
                        #pragma unroll
                        for (int c = 1; c < NC; ++c) m = fmaxf(m, xn[c]);
                        float e[NC], s = 0.f;
                        #pragma unroll
                        for (int c = 0; c < NC; ++c) { e[c] = __expf(xn[c]-m); s += e[c]; }
                        const float rs = 1.0f / s;
                        qv = make_uint4(pkbf(e[0]*rs,e[1]*rs), pkbf(e[2]*rs,e[3]*rs),
                                        pkbf(e[4]*rs,e[5]*rs), k ? cwB : cwA);
                    }
                    Q1[r1][c0+k] = qv;
                }
            }
        }
    }
    __syncthreads();

    // ---- pass 2: iter k+1 over 16x8, 4-group filter-row split ----
    {
        const int g = tid >> 7, p = tid & 127;
        const int pr = p >> 4, pc = p & 15;
        const unsigned cw = A1[pr+2*PAD][pc+2*PAD].w;
        const float c0f = lo16(cw), c1f = hi16(cw), c2f = F2a[pr+2*PAD][pc+2*PAD];
        float m2[NC];
        #pragma unroll
        for (int c = 0; c < NC; ++c) m2[c] = 0.f;

        #pragma unroll 1
        for (int ii = 0; ii < 3; ++ii) {
            const int i = g + 4*ii;
            if (i < FSZ) {
                const float* srw = &sfw[i*FSZ];
                const float* sra = &sfa[i*FSZ];
                const uint4* Qr = &Q1[pr+i][pc];
                const float* Fr = &F2a[pr+i+PAD][pc+PAD];
                #pragma unroll
                for (int j = 0; j < FSZ; ++j) {
                    const uint4 av = Qr[j];
                    const float g2 = Fr[j];
                    const float q0 = lo16(av.x), q1 = hi16(av.x);
                    const float q2 = lo16(av.y), q3 = hi16(av.y);
                    const float q4 = lo16(av.z), q5 = hi16(av.z);
                    const float g0 = lo16(av.w), g1 = hi16(av.w);
                    const float d0=c0f-g0, d1=c1f-g1, d2=c2f-g2;
                    const float tt = fmaf(d2,d2, fmaf(d1,d1, d0*d0));
                    const float af = __expf(-tt);
                    const float tf = fmaf(af, sra[j], srw[j]);
                    m2[0]=fmaf(tf,q0,m2[0]); m2[1]=fmaf(tf,q1,m2[1]);
                    m2[2]=fmaf(tf,q2,m2[2]); m2[3]=fmaf(tf,q3,m2[3]);
                    m2[4]=fmaf(tf,q4,m2[4]); m2[5]=fmaf(tf,q5,m2[5]);
                }
            }
        }
        #pragma unroll
        for (int c = 0; c < NC; ++c) pm[g][c][p] = m2[c];
    }
    __syncthreads();

    // ---- epilogue: 128 threads, one tile px each ----
    if (tid < 128) {
        const int pr = tid >> 4, pc = tid & 15;
        float xn[NC];
        #pragma unroll
        for (int c = 0; c < NC; ++c)
            xn[c] = pm[0][c][tid] + pm[1][c][tid] + pm[2][c][tid] + pm[3][c][tid];
        const int gh = h0 + pr, gw = w0 + pc;
        const float* up = xpl + (size_t)b*NC*HW + (size_t)gh*WW + gw;
        #pragma unroll
        for (int c = 0; c < NC; ++c) xn[c] += up[(size_t)c*HW];
        float m = xn[0];
        #pragma unroll
        for (int c = 1; c < NC; ++c) m = fmaxf(m, xn[c]);
        float e[NC], s = 0.f;
        #pragma unroll
        for (int c = 0; c < NC; ++c) { e[c] = __expf(xn[c]-m); s += e[c]; }
        const float rs = 1.0f / s;
        const size_t p = (size_t)(b*HH + gh)*WW + gw;
        Aout[p] = make_uint4(pkbf(e[0]*rs,e[1]*rs), pkbf(e[2]*rs,e[3]*rs),
                             pkbf(e[4]*rs,e[5]*rs), A1[pr+2*PAD][pc+2*PAD].w);
        if (FIRST) f2out[p] = F2a[pr+2*PAD][pc+2*PAD];
    }
}

// Final single iteration + log_softmax (planar out).
__global__ __launch_bounds__(BT, 4)
void crf_last(const float* __restrict__ xpl, const uint4* __restrict__ Ain,
              const float* __restrict__ f2in,
              const float* __restrict__ spac, const float* __restrict__ swp,
              const float* __restrict__ awp, const float* __restrict__ isbp,
              const float* __restrict__ iabp, float* __restrict__ outp)
{
    __shared__ uint4 Ac[MH][LA2];
    __shared__ float F2c[MH][LA2];
    __shared__ float sfw[FSZ*FSZ], sfa[FSZ*FSZ];
    __shared__ float pm[4][NC][132];

    const int tid = threadIdx.x;
    const int b  = blockIdx.z;
    const int w0 = blockIdx.x * TW;
    const int h0 = blockIdx.y * TH;

    const float swv = swp[0], awv = awp[0], isb = isbp[0];
    const float s0 = spac[b*2], s1 = spac[b*2+1];

    build_sf(tid, s0, s1, isb, swv, awv, sfw, sfa);

    for (int idx = tid; idx < MH*MW; idx += BT) {
        const int sr = idx / MW, sc = idx - (idx/MW)*MW;
        const int gh = h0 - PAD + sr, gw = w0 - PAD + sc;
        uint4 av = make_uint4(0u,0u,0u,0u);
        float f2v = 0.f;
        if (gh >= 0 && gh < HH && gw >= 0 && gw < WW) {
            const size_t p = (size_t)(b*HH + gh)*WW + gw;
            av  = Ain[p];
            f2v = f2in[p];
        }
        Ac[sr][sc]  = av;
        F2c[sr][sc] = f2v;
    }
    __syncthreads();

    {
        const int g = tid >> 7, p = tid & 127;
        const int pr = p >> 4, pc = p & 15;
        const unsigned cw = Ac[pr+PAD][pc+PAD].w;
        const float c0f = lo16(cw), c1f = hi16(cw), c2f = F2c[pr+PAD][pc+PAD];
        float m2[NC];
        #pragma unroll
        for (int c = 0; c < NC; ++c) m2[c] = 0.f;

        #pragma unroll 1
        for (int ii = 0; ii < 3; ++ii) {
            const int i = g + 4*ii;
            if (i < FSZ) {
                const float* srw = &sfw[i*FSZ];
                const float* sra = &sfa[i*FSZ];
                const uint4* Qr = &Ac[pr+i][pc];
                const float* Fr = &F2c[pr+i][pc];
                #pragma unroll
                for (int j = 0; j < FSZ; ++j) {
                    const uint4 av = Qr[j];
                    const float g2 = Fr[j];
                    const float q0 = lo16(av.x), q1 = hi16(av.x);
                    const float q2 = lo16(av.y), q3 = hi16(av.y);
                    const float q4 = lo16(av.z), q5 = hi16(av.z);
                    const float g0 = lo16(av.w), g1 = hi16(av.w);
                    const float d0=c0f-g0, d1=c1f-g1, d2=c2f-g2;
                    const float tt = fmaf(d2,d2, fmaf(d1,d1, d0*d0));
                    const float af = __expf(-tt);
                    const float tf = fmaf(af, sra[j], srw[j]);
                    m2[0]=fmaf(tf,q0,m2[0]); m2[1]=fmaf(tf,q1,m2[1]);
                    m2[2]=fmaf(tf,q2,m2[2]); m2[3]=fmaf(tf,q3,m2[3]);
                    m2[4]=fmaf(tf,q4,m2[4]); m2[5]=fmaf(tf,q5,m2[5]);
                }
            }
        }
        #pragma unroll
        for (int c = 0; c < NC; ++c) pm[g][c][p] = m2[c];
    }
    __syncthreads();

    if (tid < 128) {
        const int pr = tid >> 4, pc = tid & 15;
        float xn[NC];
        #pragma unroll
        for (int c = 0; c < NC; ++c)
            xn[c] = pm[0][c][tid] + pm[1][c][tid] + pm[2][c][tid] + pm[3][c][tid];
        const int gh = h0 + pr, gw = w0 + pc;
        const size_t pb = (size_t)b*NC*HW + (size_t)gh*WW + gw;
        #pragma unroll
        for (int c = 0; c < NC; ++c) xn[c] += xpl[pb + (size_t)c*HW];
        float m = xn[0];
        #pragma unroll
        for (int c = 1; c < NC; ++c) m = fmaxf(m, xn[c]);
        float s = 0.f;
        #pragma unroll
        for (int c = 0; c < NC; ++c) s += __expf(xn[c]-m);
        const float lg = m + __logf(s);
        #pragma unroll
        for (int c = 0; c < NC; ++c) outp[pb + (size_t)c*HW] = xn[c] - lg;
    }
}

extern "C" void kernel_launch(void* const* d_in, const int* in_sizes, int n_in,
                              void* d_out, int out_size, void* d_ws, size_t ws_size,
                              hipStream_t stream)
{
    const float* x    = (const float*)d_in[0];
    const float* fts  = (const float*)d_in[1];
    const float* spc  = (const float*)d_in[2];
    const float* swp  = (const float*)d_in[3];
    const float* awp  = (const float*)d_in[4];
    const float* isbp = (const float*)d_in[5];
    const float* iabp = (const float*)d_in[6];
    float* out = (float*)d_out;

    uint4* A0  = (uint4*)d_ws;                       // q2 slab (packed, px-major)
    uint4* A1  = A0 + (size_t)BB*HW;                 // q4 slab
    float* f2s = (float*)(A1 + (size_t)BB*HW);       // prescaled f2 slab

    dim3 grid(WW/TW, HH/TH, BB);   // 12 x 24 x 2 = 576 blocks
    dim3 blk(BT);                  // 512 threads = 8 waves

    // iters 1+2 -> A0 ; iters 3+4 -> A1 ; iter 5 -> out (log_softmax)
    crf_pair<true ><<<grid, blk, 0, stream>>>(x, A0, f2s, fts, spc, swp, awp, isbp, iabp, A0, f2s);
    crf_pair<false><<<grid, blk, 0, stream>>>(x, A0, f2s, fts, spc, swp, awp, isbp, iabp, A1, f2s);
    crf_last<<<grid, blk, 0, stream>>>(x, A1, f2s, spc, swp, awp, isbp, iabp, out);
}

// Round 8
// 89.702 us; speedup vs baseline: 1.0849x; 1.0849x over previous
//
#include <hip/hip_runtime.h>

#define HH 192
#define WW 192
#define BB 2
#define NC 6
#define FSZ 11
#define PAD 5
#define NT (FSZ*FSZ)       // 121 taps
#define TW 16
#define TH 8
#define SWD 26             // staged cols (16 + 2*5)
#define SHT 18             // staged rows (8 + 2*5)
#define LA 27              // LDS row stride
#define HW (HH*WW)
#define BT 256             // 4 waves

// bf16 pack/unpack (round-half-up)
__device__ __forceinline__ unsigned pkbf(float a, float b) {
    unsigned ua = (__float_as_uint(a) + 0x8000u) >> 16;
    unsigned ub = (__float_as_uint(b) + 0x8000u) & 0xffff0000u;
    return ua | ub;
}
__device__ __forceinline__ float lo16(unsigned u){ return __uint_as_float(u << 16); }
__device__ __forceinline__ float hi16(unsigned u){ return __uint_as_float(u & 0xffff0000u); }

// ---------------------------------------------------------------------------
// Precompute total_filter[b][t][h][w] = sf[t]*(sw + aw*af(px,t))  (f32).
// Iteration-invariant (depends only on features). Tap-major so iter-kernel
// loads are lane-coalesced. Center tap (t=60) = 0 via sf=0.
// Tile 16x8, 256 threads: wave-pair 0 does tap rows 0..5, pair 1 rows 6..10.
// ---------------------------------------------------------------------------
__global__ __launch_bounds__(BT)
void crf_filt(const float* __restrict__ feats, const float* __restrict__ spac,
              const float* __restrict__ swp, const float* __restrict__ awp,
              const float* __restrict__ isbp, const float* __restrict__ iabp,
              float* __restrict__ filt)
{
    __shared__ float2 F01[SHT][LA];
    __shared__ float  F2s[SHT][LA];
    __shared__ float  sfw[NT], sfa[NT];

    const int tid = threadIdx.x;
    const int b  = blockIdx.z;
    const int w0 = blockIdx.x * TW;
    const int h0 = blockIdx.y * TH;

    const float swv = swp[0], awv = awp[0], isb = isbp[0], iab = iabp[0];
    const float s0 = spac[b*2], s1 = spac[b*2+1];
    const float kapp = -0.5f * iab * iab;

    if (tid < NT) {
        const int fi = tid / FSZ, fj = tid - (tid/FSZ)*FSZ;
        const float ri = (float)(fi-PAD) * s0 * isb;
        const float rj = (float)(fj-PAD) * s1 * isb;
        float sf = __expf(-0.5f*(ri*ri + rj*rj));
        if (fi == PAD && fj == PAD) sf = 0.f;
        sfw[tid] = sf * swv;
        sfa[tid] = sf * awv;
    }

    const float* fb = feats + (size_t)b*3*HW;
    for (int idx = tid; idx < SHT*SWD; idx += BT) {
        const int sr = idx / SWD, sc = idx - (idx/SWD)*SWD;
        const int gh = h0 + sr - PAD, gw = w0 + sc - PAD;
        float g0=0.f, g1=0.f, g2=0.f;
        if (gh >= 0 && gh < HH && gw >= 0 && gw < WW) {
            const int off = gh*WW + gw;
            g0 = fb[off]; g1 = fb[off+HW]; g2 = fb[off+2*HW];
        }
        F01[sr][sc] = make_float2(g0,g1);
        F2s[sr][sc] = g2;
    }
    __syncthreads();

    const int g2g = tid >> 7;          // 0: tap rows 0..5 ; 1: rows 6..10
    const int p   = tid & 127;
    const int ry  = p >> 4;            // 0..7
    const int tx  = p & 15;            // 0..15
    const int gh  = h0 + ry, gw = w0 + tx;

    const float2 c01 = F01[ry+PAD][tx+PAD];
    const float  c2  = F2s[ry+PAD][tx+PAD];

    float* fo = filt + (size_t)b*NT*HW + (size_t)gh*WW + gw;

    const int i0 = g2g ? 6 : 0;
    const int i1 = g2g ? FSZ : 6;
    #pragma unroll 1
    for (int i = i0; i < i1; ++i) {
        #pragma unroll
        for (int j = 0; j < FSZ; ++j) {
            const int t = i*FSZ + j;
            const float2 g01 = F01[ry+i][tx+j];
            const float  g2v = F2s[ry+i][tx+j];
            const float d0 = c01.x-g01.x, d1 = c01.y-g01.y, d2 = c2-g2v;
            const float tt = fmaf(d2,d2, fmaf(d1,d1, d0*d0));
            const float af = __expf(tt * kapp);
            fo[(size_t)t*HW] = fmaf(af, sfa[t], sfw[t]);
        }
    }
}

// ---------------------------------------------------------------------------
// One mean-field iteration using the precomputed filter.
//   FIRST: staging reads planar x (softmax on the fly); else packed q slab.
//   LAST : writes planar log_softmax; else packed q slab.
// 256 threads: wave-pair 0 = tap rows 0..5, pair 1 = rows 6..10; pm-reduce.
// ---------------------------------------------------------------------------
template<bool FIRST, bool LAST>
__global__ __launch_bounds__(BT)
void crf_it(const float* __restrict__ xpl, const uint4* __restrict__ Ain,
            const float* __restrict__ filt,
            uint4* __restrict__ Aout, float* __restrict__ outp)
{
    __shared__ uint4 As[SHT][LA];        // q01,q23,q45 (bf16x2), .w unused
    __shared__ float pm[2][NC][128];     // partial msgs per wave-pair

    const int tid = threadIdx.x;
    const int b  = blockIdx.z;
    const int w0 = blockIdx.x * TW;
    const int h0 = blockIdx.y * TH;

    // ---- stage q tile + halo (zeros outside image) ----
    for (int idx = tid; idx < SHT*SWD; idx += BT) {
        const int sr = idx / SWD, sc = idx - (idx/SWD)*SWD;
        const int gh = h0 + sr - PAD, gw = w0 + sc - PAD;
        uint4 av = make_uint4(0u,0u,0u,0u);
        if (gh >= 0 && gh < HH && gw >= 0 && gw < WW) {
            if (FIRST) {
                const float* xb = xpl + (size_t)b*NC*HW + gh*WW + gw;
                const float v0 = xb[0], v1 = xb[HW], v2 = xb[2*HW];
                const float v3 = xb[3*HW], v4 = xb[4*HW], v5 = xb[5*HW];
                float m = fmaxf(fmaxf(fmaxf(v0,v1),fmaxf(v2,v3)),fmaxf(v4,v5));
                float q0=__expf(v0-m), q1=__expf(v1-m), q2=__expf(v2-m);
                float q3=__expf(v3-m), q4=__expf(v4-m), q5=__expf(v5-m);
                const float rs = 1.0f/(q0+q1+q2+q3+q4+q5);
                av = make_uint4(pkbf(q0*rs,q1*rs), pkbf(q2*rs,q3*rs),
                                pkbf(q4*rs,q5*rs), 0u);
            } else {
                av = Ain[(size_t)(b*HH + gh)*WW + gw];
            }
        }
        As[sr][sc] = av;
    }
    __syncthreads();

    const int g2g = tid >> 7;          // 0: tap rows 0..5 ; 1: rows 6..10
    const int p   = tid & 127;
    const int ry  = p >> 4;
    const int tx  = p & 15;
    const int gh  = h0 + ry, gw = w0 + tx;

    const float* fbase = filt + (size_t)b*NT*HW + (size_t)gh*WW + gw;

    float msg[NC];
    #pragma unroll
    for (int c = 0; c < NC; ++c) msg[c] = 0.f;

    const int i0 = g2g ? 6 : 0;
    const int i1 = g2g ? FSZ : 6;
    #pragma unroll 2
    for (int i = i0; i < i1; ++i) {
        const int r = ry + i;
        #pragma unroll
        for (int j = 0; j < FSZ; ++j) {
            const uint4 av = As[r][tx+j];
            const float tf = fbase[(size_t)(i*FSZ + j)*HW];
            msg[0] = fmaf(tf, lo16(av.x), msg[0]);
            msg[1] = fmaf(tf, hi16(av.x), msg[1]);
            msg[2] = fmaf(tf, lo16(av.y), msg[2]);
            msg[3] = fmaf(tf, hi16(av.y), msg[3]);
            msg[4] = fmaf(tf, lo16(av.z), msg[4]);
            msg[5] = fmaf(tf, hi16(av.z), msg[5]);
        }
    }

    #pragma unroll
    for (int c = 0; c < NC; ++c) pm[g2g][c][p] = msg[c];
    __syncthreads();

    // ---- epilogue: 128 threads, one px each ----
    if (tid < 128) {
        const int pr = tid >> 4, pc = tid & 15;
        const int oh = h0 + pr, ow = w0 + pc;
        const size_t pb = (size_t)b*NC*HW + (size_t)oh*WW + ow;
        float xn[NC];
        #pragma unroll
        for (int c = 0; c < NC; ++c)
            xn[c] = pm[0][c][tid] + pm[1][c][tid] + xpl[pb + (size_t)c*HW];

        float m = xn[0];
        #pragma unroll
        for (int c = 1; c < NC; ++c) m = fmaxf(m, xn[c]);

        if (LAST) {
            float s = 0.f;
            #pragma unroll
            for (int c = 0; c < NC; ++c) s += __expf(xn[c]-m);
            const float lg = m + __logf(s);
            #pragma unroll
            for (int c = 0; c < NC; ++c) outp[pb + (size_t)c*HW] = xn[c] - lg;
        } else {
            float e[NC], s = 0.f;
            #pragma unroll
            for (int c = 0; c < NC; ++c) { e[c] = __expf(xn[c]-m); s += e[c]; }
            const float rs = 1.0f / s;
            Aout[(size_t)(b*HH + oh)*WW + ow] =
                make_uint4(pkbf(e[0]*rs,e[1]*rs), pkbf(e[2]*rs,e[3]*rs),
                           pkbf(e[4]*rs,e[5]*rs), 0u);
        }
    }
}

extern "C" void kernel_launch(void* const* d_in, const int* in_sizes, int n_in,
                              void* d_out, int out_size, void* d_ws, size_t ws_size,
                              hipStream_t stream)
{
    const float* x    = (const float*)d_in[0];
    const float* fts  = (const float*)d_in[1];
    const float* spc  = (const float*)d_in[2];
    const float* swp  = (const float*)d_in[3];
    const float* awp  = (const float*)d_in[4];
    const float* isbp = (const float*)d_in[5];
    const float* iabp = (const float*)d_in[6];
    float* out = (float*)d_out;

    float* filt = (float*)d_ws;                          // 35.7 MB  [b][t][h][w]
    uint4* A0   = (uint4*)((char*)d_ws + (size_t)BB*NT*HW*sizeof(float));
    uint4* A1   = A0 + (size_t)BB*HW;                    // 1.18 MB each

    dim3 grid(WW/TW, HH/TH, BB);   // 12 x 24 x 2 = 576 blocks
    dim3 blk(BT);                  // 256 threads = 4 waves

    crf_filt<<<grid, blk, 0, stream>>>(fts, spc, swp, awp, isbp, iabp, filt);
    crf_it<true ,false><<<grid, blk, 0, stream>>>(x, A1, filt, A0, out);
    crf_it<false,false><<<grid, blk, 0, stream>>>(x, A0, filt, A1, out);
    crf_it<false,false><<<grid, blk, 0, stream>>>(x, A1, filt, A0, out);
    crf_it<false,false><<<grid, blk, 0, stream>>>(x, A0, filt, A1, out);
    crf_it<false,true ><<<grid, blk, 0, stream>>>(x, A1, filt, A0, out);
}